// Round 11
// baseline (1231.602 us; speedup 1.0000x reference)
//
#include <hip/hip_runtime.h>
#include <hip/hip_bf16.h>

typedef __bf16 bf16x8 __attribute__((ext_vector_type(8)));
typedef float f32x4 __attribute__((ext_vector_type(4)));

#define AS1(p) ((const __attribute__((address_space(1))) void*)(p))
#define AS3(p) ((__attribute__((address_space(3))) void*)(p))

// ---------------- tiled cast+transpose fp32(L,K,N) -> bf16(L,N,K) --------
__global__ __launch_bounds__(256) void transpose32(const float* __restrict__ W,
                                                   __bf16* __restrict__ WT,
                                                   int K, int N) {
  __shared__ float t[32][33];
  int l = blockIdx.z;
  int k0 = blockIdx.y * 32, n0 = blockIdx.x * 32;
  int tx = threadIdx.x & 31, ty = threadIdx.x >> 5;
  const float* src = W + ((size_t)l * K + k0) * N + n0;
#pragma unroll
  for (int i = 0; i < 32; i += 8) t[ty + i][tx] = src[(size_t)(ty + i) * N + tx];
  __syncthreads();
  __bf16* dst = WT + ((size_t)l * N + n0) * K + k0;
#pragma unroll
  for (int i = 0; i < 32; i += 8) dst[(size_t)(ty + i) * K + tx] = (__bf16)t[tx][ty + i];
}

// ---------------- LayerNorm: fp32 row(512) -> bf16 ----------------------
__global__ __launch_bounds__(256) void ln_kernel(const float* __restrict__ x,
                                                 const float* __restrict__ gamma,
                                                 const float* __restrict__ beta,
                                                 __bf16* __restrict__ y) {
  int wave = threadIdx.x >> 6, lane = threadIdx.x & 63;
  size_t row = (size_t)blockIdx.x * 4 + wave;
  const float* xr = x + row * 512 + lane * 8;
  float4 v0 = *(const float4*)xr;
  float4 v1 = *(const float4*)(xr + 4);
  float s = v0.x + v0.y + v0.z + v0.w + v1.x + v1.y + v1.z + v1.w;
  float ss = v0.x * v0.x + v0.y * v0.y + v0.z * v0.z + v0.w * v0.w +
             v1.x * v1.x + v1.y * v1.y + v1.z * v1.z + v1.w * v1.w;
#pragma unroll
  for (int m = 1; m < 64; m <<= 1) {
    s += __shfl_xor(s, m);
    ss += __shfl_xor(ss, m);
  }
  float mean = s * (1.f / 512.f);
  float var = ss * (1.f / 512.f) - mean * mean;
  float rstd = rsqrtf(var + 1e-5f);
  const float* gp = gamma + lane * 8;
  const float* bp = beta + lane * 8;
  float4 g0 = *(const float4*)gp, g1 = *(const float4*)(gp + 4);
  float4 b0 = *(const float4*)bp, b1 = *(const float4*)(bp + 4);
  bf16x8 o;
  o[0] = (__bf16)((v0.x - mean) * rstd * g0.x + b0.x);
  o[1] = (__bf16)((v0.y - mean) * rstd * g0.y + b0.y);
  o[2] = (__bf16)((v0.z - mean) * rstd * g0.z + b0.z);
  o[3] = (__bf16)((v0.w - mean) * rstd * g0.w + b0.w);
  o[4] = (__bf16)((v1.x - mean) * rstd * g1.x + b1.x);
  o[5] = (__bf16)((v1.y - mean) * rstd * g1.y + b1.y);
  o[6] = (__bf16)((v1.z - mean) * rstd * g1.z + b1.z);
  o[7] = (__bf16)((v1.w - mean) * rstd * g1.w + b1.w);
  *(bf16x8*)(y + row * 512 + lane * 8) = o;
}

// ======== shared epilogue for both gemm256 variants: two-pass stride-72 ====
#define GEMM256_EPILOGUE()                                                      \
  __syncthreads();                                                              \
  __bf16* lw = (__bf16*)(lds + w * 9216);                                       \
  int crow0 = tileM * 256 + wave_m * 128;                                       \
  int ccol = tileN * 256 + wave_n * 64 + (l & 7) * 8;                           \
  _Pragma("unroll") for (int half = 0; half < 2; ++half) {                      \
    _Pragma("unroll") for (int m2 = 0; m2 < 4; ++m2) {                          \
      int mf = half * 4 + m2;                                                   \
      _Pragma("unroll") for (int nf = 0; nf < 4; ++nf)                          \
        _Pragma("unroll") for (int r = 0; r < 4; ++r)                           \
          lw[(m2 * 16 + lh * 4 + r) * 72 + nf * 16 + lm] = (__bf16)acc[mf][nf][r]; \
    }                                                                           \
    asm volatile("s_waitcnt lgkmcnt(0)" ::: "memory");                          \
    __builtin_amdgcn_sched_barrier(0);                                          \
    _Pragma("unroll") for (int p = 0; p < 8; ++p) {                             \
      int lrow = p * 8 + (l >> 3);                                              \
      bf16x8 v = *(const bf16x8*)&lw[lrow * 72 + (l & 7) * 8];                  \
      *(bf16x8*)&Cb[(size_t)(crow0 + half * 64 + lrow) * NCOLS + ccol] = v;     \
    }                                                                           \
    asm volatile("s_waitcnt lgkmcnt(0)" ::: "memory");                          \
    __builtin_amdgcn_sched_barrier(0);                                          \
  }

// ---------------- Variant A: 256x256, BK=64, double-buffer (R7 schedule) --
#define STAGE_PART(kt_, part_)                                                   \
  {                                                                              \
    const __bf16* gb_ = ((part_) < 2) ? Abase : Bbase;                           \
    int rowoff_ = ((part_)&1) * 128;                                             \
    const __bf16* g0_ = gb_ + (size_t)(rowoff_ + r0s) * 512 + (kt_)*64 + s0 * 8; \
    const __bf16* g1_ = gb_ + (size_t)(rowoff_ + r1s) * 512 + (kt_)*64 + s1 * 8; \
    char* lb_ = lds + (((kt_)&1) * 65536) + ((part_)*16384);                     \
    __builtin_amdgcn_global_load_lds(AS1(g0_), AS3(lb_ + ldsw0), 16, 0, 0);      \
    __builtin_amdgcn_global_load_lds(AS1(g1_), AS3(lb_ + ldsw1), 16, 0, 0);      \
  }

template <int NCOLS>
__global__ __launch_bounds__(512, 2) void gemm256(const __bf16* __restrict__ A,
                                                  const __bf16* __restrict__ BT,
                                                  __bf16* __restrict__ Cb) {
  extern __shared__ __attribute__((aligned(128))) char lds[];
  constexpr int NT = NCOLS / 256;
  int bid = blockIdx.x;
  int cpx = gridDim.x >> 3;
  int L = (bid & 7) * cpx + (bid >> 3);
  int tileM = L / NT, tileN = L - tileM * NT;
  int tid = threadIdx.x;
  int l = tid & 63, w = tid >> 6;
  int lm = l & 15, lh = l >> 4;
  int wave_m = w >> 2, wave_n = w & 3;
  const __bf16* Abase = A + (size_t)tileM * 256 * 512;
  const __bf16* Bbase = BT + (size_t)tileN * 256 * 512;
  int r0s = tid >> 3, s0 = (tid & 7) ^ (r0s & 7);
  int p1 = tid + 512;
  int r1s = p1 >> 3, s1 = (p1 & 7) ^ (r1s & 7);
  int ldsw0 = (w * 64) * 16, ldsw1 = (512 + w * 64) * 16;

  f32x4 acc[8][4];
#pragma unroll
  for (int m = 0; m < 8; ++m)
#pragma unroll
    for (int n = 0; n < 4; ++n) acc[m][n] = (f32x4){0.f, 0.f, 0.f, 0.f};

  int xorv = (lm & 7) << 4;
  int kb0 = (lh * 16) ^ xorv;
  int kb1 = (64 + lh * 16) ^ xorv;
  int arow = wave_m * 128 + lm;
  int brow = wave_n * 64 + lm;

  STAGE_PART(0, 0); STAGE_PART(0, 1); STAGE_PART(0, 2); STAGE_PART(0, 3);

  for (int kt = 0; kt < 8; ++kt) {
    char* sb = lds + (kt & 1) * 65536;
    if (kt < 7) {
      STAGE_PART(kt + 1, 0);
      asm volatile("s_waitcnt vmcnt(2)" ::: "memory");
    } else {
      asm volatile("s_waitcnt vmcnt(0)" ::: "memory");
    }
    __builtin_amdgcn_sched_barrier(0);
    __builtin_amdgcn_s_barrier();
    bf16x8 bfrag[4][2];
#pragma unroll
    for (int nf = 0; nf < 4; ++nf) {
      const char* bp = sb + 32768 + (brow + nf * 16) * 128;
      bfrag[nf][0] = *(const bf16x8*)(bp + kb0);
      bfrag[nf][1] = *(const bf16x8*)(bp + kb1);
    }
#pragma unroll
    for (int ph = 0; ph < 4; ++ph) {
      bf16x8 af[2][2];
#pragma unroll
      for (int m = 0; m < 2; ++m) {
        const char* ap = sb + (arow + (ph * 2 + m) * 16) * 128;
        af[m][0] = *(const bf16x8*)(ap + kb0);
        af[m][1] = *(const bf16x8*)(ap + kb1);
      }
      if (ph == 0 && kt < 7) STAGE_PART(kt + 1, 1);
      if (ph == 1 && kt < 7) STAGE_PART(kt + 1, 2);
      if (ph == 2 && kt < 7) STAGE_PART(kt + 1, 3);
      __builtin_amdgcn_s_setprio(1);
#pragma unroll
      for (int m = 0; m < 2; ++m)
#pragma unroll
        for (int nf = 0; nf < 4; ++nf) {
          acc[ph * 2 + m][nf] = __builtin_amdgcn_mfma_f32_16x16x32_bf16(
              af[m][0], bfrag[nf][0], acc[ph * 2 + m][nf], 0, 0, 0);
          acc[ph * 2 + m][nf] = __builtin_amdgcn_mfma_f32_16x16x32_bf16(
              af[m][1], bfrag[nf][1], acc[ph * 2 + m][nf], 0, 0, 0);
        }
      __builtin_amdgcn_s_setprio(0);
    }
    __builtin_amdgcn_s_barrier();
  }

  GEMM256_EPILOGUE()
}

// ---------------- Variant B: 256x256, BK=64, SINGLE-buffer, 2 blocks/CU ----
// Cross-block TLP hiding: staging stall exposed per block, covered by the
// co-resident block's compute phase. 72 KiB LDS -> 2 blocks/CU (144 of 160).
#define STAGE_SB(kt_, part_)                                                     \
  {                                                                              \
    const __bf16* gb_ = ((part_) < 2) ? Abase : Bbase;                           \
    int rowoff_ = ((part_)&1) * 128;                                             \
    const __bf16* g0_ = gb_ + (size_t)(rowoff_ + r0s) * 512 + (kt_)*64 + s0 * 8; \
    const __bf16* g1_ = gb_ + (size_t)(rowoff_ + r1s) * 512 + (kt_)*64 + s1 * 8; \
    char* lb_ = lds + ((part_)*16384);                                           \
    __builtin_amdgcn_global_load_lds(AS1(g0_), AS3(lb_ + ldsw0), 16, 0, 0);      \
    __builtin_amdgcn_global_load_lds(AS1(g1_), AS3(lb_ + ldsw1), 16, 0, 0);      \
  }

template <int NCOLS>
__global__ __launch_bounds__(512, 4) void gemm256_sb(const __bf16* __restrict__ A,
                                                     const __bf16* __restrict__ BT,
                                                     __bf16* __restrict__ Cb) {
  extern __shared__ __attribute__((aligned(128))) char lds[];
  constexpr int NT = NCOLS / 256;
  int bid = blockIdx.x;
  int cpx = gridDim.x >> 3;
  int L = (bid & 7) * cpx + (bid >> 3);
  int tileM = L / NT, tileN = L - tileM * NT;
  int tid = threadIdx.x;
  int l = tid & 63, w = tid >> 6;
  int lm = l & 15, lh = l >> 4;
  int wave_m = w >> 2, wave_n = w & 3;
  const __bf16* Abase = A + (size_t)tileM * 256 * 512;
  const __bf16* Bbase = BT + (size_t)tileN * 256 * 512;
  int r0s = tid >> 3, s0 = (tid & 7) ^ (r0s & 7);
  int p1 = tid + 512;
  int r1s = p1 >> 3, s1 = (p1 & 7) ^ (r1s & 7);
  int ldsw0 = (w * 64) * 16, ldsw1 = (512 + w * 64) * 16;

  f32x4 acc[8][4];
#pragma unroll
  for (int m = 0; m < 8; ++m)
#pragma unroll
    for (int n = 0; n < 4; ++n) acc[m][n] = (f32x4){0.f, 0.f, 0.f, 0.f};

  int xorv = (lm & 7) << 4;
  int kb0 = (lh * 16) ^ xorv;
  int kb1 = (64 + lh * 16) ^ xorv;
  int arow = wave_m * 128 + lm;
  int brow = wave_n * 64 + lm;

  // prologue: stage K-tile 0, wait, sync
  STAGE_SB(0, 0); STAGE_SB(0, 1); STAGE_SB(0, 2); STAGE_SB(0, 3);
  asm volatile("s_waitcnt vmcnt(0)" ::: "memory");
  __builtin_amdgcn_sched_barrier(0);
  __builtin_amdgcn_s_barrier();

  for (int kt = 0; kt < 8; ++kt) {
    const char* sb = lds;
    bf16x8 bfrag[4][2];
#pragma unroll
    for (int nf = 0; nf < 4; ++nf) {
      const char* bp = sb + 32768 + (brow + nf * 16) * 128;
      bfrag[nf][0] = *(const bf16x8*)(bp + kb0);
      bfrag[nf][1] = *(const bf16x8*)(bp + kb1);
    }
#pragma unroll
    for (int ph = 0; ph < 4; ++ph) {
      bf16x8 af[2][2];
#pragma unroll
      for (int m = 0; m < 2; ++m) {
        const char* ap = sb + (arow + (ph * 2 + m) * 16) * 128;
        af[m][0] = *(const bf16x8*)(ap + kb0);
        af[m][1] = *(const bf16x8*)(ap + kb1);
      }
      __builtin_amdgcn_s_setprio(1);
#pragma unroll
      for (int m = 0; m < 2; ++m)
#pragma unroll
        for (int nf = 0; nf < 4; ++nf) {
          acc[ph * 2 + m][nf] = __builtin_amdgcn_mfma_f32_16x16x32_bf16(
              af[m][0], bfrag[nf][0], acc[ph * 2 + m][nf], 0, 0, 0);
          acc[ph * 2 + m][nf] = __builtin_amdgcn_mfma_f32_16x16x32_bf16(
              af[m][1], bfrag[nf][1], acc[ph * 2 + m][nf], 0, 0, 0);
        }
      __builtin_amdgcn_s_setprio(0);
    }
    // all reads of the slot are retired (data-dep) — make it explicit, then sync
    asm volatile("s_waitcnt lgkmcnt(0)" ::: "memory");
    __builtin_amdgcn_sched_barrier(0);
    __builtin_amdgcn_s_barrier();  // every wave done READING the slot
    if (kt < 7) {
      STAGE_SB(kt + 1, 0); STAGE_SB(kt + 1, 1);
      STAGE_SB(kt + 1, 2); STAGE_SB(kt + 1, 3);
      asm volatile("s_waitcnt vmcnt(0)" ::: "memory");
      __builtin_amdgcn_sched_barrier(0);
      __builtin_amdgcn_s_barrier();  // slot refilled for all waves
    }
  }

  GEMM256_EPILOGUE()
}

// ---------------- 128x128 GEMM + fused bias/residual, 8 waves (R9) -------
#define STAGE128(kt_, part_)                                                    \
  {                                                                             \
    const __bf16* gb_ = ((part_) == 0) ? Abase : Bbase;                         \
    const __bf16* g0_ = gb_ + (size_t)r0s * 512 + (kt_)*64 + s0 * 8;            \
    const __bf16* g1_ = gb_ + (size_t)r1s * 512 + (kt_)*64 + s1 * 8;            \
    char* lb_ = lds + (((kt_)&1) * 32768) + ((part_)*16384);                    \
    __builtin_amdgcn_global_load_lds(AS1(g0_), AS3(lb_ + ldsw0), 16, 0, 0);     \
    __builtin_amdgcn_global_load_lds(AS1(g1_), AS3(lb_ + ldsw1), 16, 0, 0);     \
  }

__global__ __launch_bounds__(512, 4) void gemm128res(const __bf16* __restrict__ A,
                                                     const __bf16* __restrict__ BT,
                                                     float* Cf,
                                                     const float* __restrict__ bias,
                                                     const float* Resid) {
  extern __shared__ __attribute__((aligned(128))) char lds[];
  constexpr int NCOLS = 512;
  constexpr int NT = 4;
  int bid = blockIdx.x;
  int cpx = gridDim.x >> 3;
  int L = (bid & 7) * cpx + (bid >> 3);
  int tileM = L / NT, tileN = L - tileM * NT;
  int tid = threadIdx.x;
  int l = tid & 63, w = tid >> 6;
  int lm = l & 15, lh = l >> 4;
  int wave_m = w >> 2, wave_n = w & 3;
  const __bf16* Abase = A + (size_t)tileM * 128 * 512;
  const __bf16* Bbase = BT + (size_t)tileN * 128 * 512;
  int r0s = tid >> 3, s0 = (tid & 7) ^ (r0s & 7);
  int p1 = tid + 512;
  int r1s = p1 >> 3, s1 = (p1 & 7) ^ (r1s & 7);
  int ldsw0 = (w * 64) * 16, ldsw1 = 8192 + (w * 64) * 16;

  f32x4 acc[4][2];
#pragma unroll
  for (int m = 0; m < 4; ++m)
#pragma unroll
    for (int n = 0; n < 2; ++n) acc[m][n] = (f32x4){0.f, 0.f, 0.f, 0.f};

  int xorv = (lm & 7) << 4;
  int kb0 = (lh * 16) ^ xorv;
  int kb1 = (64 + lh * 16) ^ xorv;
  int arow = wave_m * 64 + lm;
  int brow = wave_n * 32 + lm;

  STAGE128(0, 0); STAGE128(0, 1);

  for (int kt = 0; kt < 8; ++kt) {
    char* sb = lds + (kt & 1) * 32768;
    if (kt < 7) {
      STAGE128(kt + 1, 0);
      asm volatile("s_waitcnt vmcnt(2)" ::: "memory");
    } else {
      asm volatile("s_waitcnt vmcnt(0)" ::: "memory");
    }
    __builtin_amdgcn_sched_barrier(0);
    __builtin_amdgcn_s_barrier();
    bf16x8 bfrag[2][2];
#pragma unroll
    for (int nf = 0; nf < 2; ++nf) {
      const char* bp = sb + 16384 + (brow + nf * 16) * 128;
      bfrag[nf][0] = *(const bf16x8*)(bp + kb0);
      bfrag[nf][1] = *(const bf16x8*)(bp + kb1);
    }
    bf16x8 af[4][2];
#pragma unroll
    for (int mf = 0; mf < 4; ++mf) {
      const char* ap = sb + (arow + mf * 16) * 128;
      af[mf][0] = *(const bf16x8*)(ap + kb0);
      af[mf][1] = *(const bf16x8*)(ap + kb1);
    }
    if (kt < 7) STAGE128(kt + 1, 1);
    __builtin_amdgcn_s_setprio(1);
#pragma unroll
    for (int mf = 0; mf < 4; ++mf)
#pragma unroll
      for (int nf = 0; nf < 2; ++nf) {
        acc[mf][nf] = __builtin_amdgcn_mfma_f32_16x16x32_bf16(af[mf][0], bfrag[nf][0],
                                                              acc[mf][nf], 0, 0, 0);
        acc[mf][nf] = __builtin_amdgcn_mfma_f32_16x16x32_bf16(af[mf][1], bfrag[nf][1],
                                                              acc[mf][nf], 0, 0, 0);
      }
    __builtin_amdgcn_s_setprio(0);
    __builtin_amdgcn_s_barrier();
  }

  float* lf = (float*)(lds + w * 2560);
  int crow0 = tileM * 128 + wave_m * 64;
  int ccol0 = tileN * 128 + wave_n * 32;
  int erow = l >> 2;
  int ecl = (l & 3) * 8;
  float4 ba = *(const float4*)(bias + ccol0 + ecl);
  float4 bb = *(const float4*)(bias + ccol0 + ecl + 4);
#pragma unroll
  for (int mf = 0; mf < 4; ++mf) {
#pragma unroll
    for (int nf = 0; nf < 2; ++nf)
#pragma unroll
      for (int r = 0; r < 4; ++r)
        lf[(lh * 4 + r) * 40 + nf * 16 + lm] = acc[mf][nf][r];
    size_t rowg = (size_t)(crow0 + mf * 16 + erow);
    const float* rp = Resid + rowg * NCOLS + ccol0 + ecl;
    float* cp = Cf + rowg * NCOLS + ccol0 + ecl;
    float4 a0 = *(float4*)&lf[erow * 40 + ecl];
    float4 a1 = *(float4*)&lf[erow * 40 + ecl + 4];
    float4 r0 = *(const float4*)rp;
    float4 r1 = *(const float4*)(rp + 4);
    float4 o0, o1;
    o0.x = a0.x + ba.x + r0.x; o0.y = a0.y + ba.y + r0.y;
    o0.z = a0.z + ba.z + r0.z; o0.w = a0.w + ba.w + r0.w;
    o1.x = a1.x + bb.x + r1.x; o1.y = a1.y + bb.y + r1.y;
    o1.z = a1.z + bb.z + r1.z; o1.w = a1.w + bb.w + r1.w;
    *(float4*)cp = o0;
    *(float4*)(cp + 4) = o1;
  }
}

// ---------------- Spatial attention: per (b, h<4, t) block ----------------
__global__ __launch_bounds__(256) void attn_spatial(const __bf16* __restrict__ qkv,
                                                    __bf16* __restrict__ attn_out) {
  __shared__ __attribute__((aligned(16))) __bf16 VT[64 * 256];
  __shared__ __attribute__((aligned(16))) __bf16 P[4][4096];
  int bid = blockIdx.x;
  int b = bid >> 6;
  int rem = bid & 63;
  int h = rem >> 4;
  int t = rem & 15;
  int tid = threadIdx.x;
  int w = tid >> 6, l = tid & 63;
  size_t nbase = (size_t)b * 4096 + t * 256;
#pragma unroll
  for (int i = 0; i < 8; i++) {
    int idx = tid + i * 256;
    int key = idx >> 3, dseg = idx & 7;
    bf16x8 v = *(const bf16x8*)(qkv + (nbase + key) * 1536 + 1024 + h * 64 + dseg * 8);
#pragma unroll
    for (int d2 = 0; d2 < 8; d2++) {
      int dh = dseg * 8 + d2;
      VT[dh * 256 + (((key >> 3) ^ (dh & 7)) << 3) + (key & 7)] = v[d2];
    }
  }
  __syncthreads();
  int lm = l & 15, lh = l >> 4;
  for (int it = 0; it < 4; ++it) {
    int qbase = it * 64 + w * 16;
    const __bf16* qp = qkv + (nbase + qbase + lm) * 1536 + h * 64 + lh * 8;
    bf16x8 aq0 = *(const bf16x8*)qp;
    bf16x8 aq1 = *(const bf16x8*)(qp + 32);
    f32x4 sa[16];
#pragma unroll
    for (int tn = 0; tn < 16; ++tn) {
      const __bf16* kp = qkv + (nbase + tn * 16 + lm) * 1536 + 512 + h * 64 + lh * 8;
      bf16x8 bk0 = *(const bf16x8*)kp;
      bf16x8 bk1 = *(const bf16x8*)(kp + 32);
      f32x4 z = {0.f, 0.f, 0.f, 0.f};
      z = __builtin_amdgcn_mfma_f32_16x16x32_bf16(aq0, bk0, z, 0, 0, 0);
      sa[tn] = __builtin_amdgcn_mfma_f32_16x16x32_bf16(aq1, bk1, z, 0, 0, 0);
    }
    float rmax[4] = {-1e30f, -1e30f, -1e30f, -1e30f};
#pragma unroll
    for (int tn = 0; tn < 16; ++tn)
#pragma unroll
      for (int r = 0; r < 4; ++r) {
        sa[tn][r] *= 0.125f;
        rmax[r] = fmaxf(rmax[r], sa[tn][r]);
      }
#pragma unroll
    for (int m = 1; m < 16; m <<= 1)
#pragma unroll
      for (int r = 0; r < 4; ++r) rmax[r] = fmaxf(rmax[r], __shfl_xor(rmax[r], m));
    float rsum[4] = {0.f, 0.f, 0.f, 0.f};
#pragma unroll
    for (int tn = 0; tn < 16; ++tn)
#pragma unroll
      for (int r = 0; r < 4; ++r) {
        float e = __expf(sa[tn][r] - rmax[r]);
        sa[tn][r] = e;
        rsum[r] += e;
      }
#pragma unroll
    for (int m = 1; m < 16; m <<= 1)
#pragma unroll
      for (int r = 0; r < 4; ++r) rsum[r] += __shfl_xor(rsum[r], m);
    float rinv[4];
#pragma unroll
    for (int r = 0; r < 4; ++r) rinv[r] = 1.f / rsum[r];
#pragma unroll
    for (int tn = 0; tn < 16; ++tn)
#pragma unroll
      for (int r = 0; r < 4; ++r) {
        int row = lh * 4 + r;
        int col = tn * 16 + lm;
        P[w][row * 256 + ((((col >> 3)) ^ (row & 7)) << 3) + (col & 7)] =
            (__bf16)(sa[tn][r] * rinv[r]);
      }
    f32x4 oa[4];
#pragma unroll
    for (int nt = 0; nt < 4; ++nt) oa[nt] = (f32x4){0.f, 0.f, 0.f, 0.f};
#pragma unroll
    for (int kc = 0; kc < 8; ++kc) {
      bf16x8 pa = *(const bf16x8*)&P[w][lm * 256 + (((kc * 4 + lh) ^ (lm & 7)) << 3)];
#pragma unroll
      for (int nt = 0; nt < 4; ++nt) {
        int dh = nt * 16 + lm;
        bf16x8 bv = *(const bf16x8*)&VT[dh * 256 + (((kc * 4 + lh) ^ (dh & 7)) << 3)];
        oa[nt] = __builtin_amdgcn_mfma_f32_16x16x32_bf16(pa, bv, oa[nt], 0, 0, 0);
      }
    }
#pragma unroll
    for (int nt = 0; nt < 4; ++nt)
#pragma unroll
      for (int r = 0; r < 4; ++r) {
        size_t row = nbase + qbase + lh * 4 + r;
        attn_out[row * 512 + h * 64 + nt * 16 + lm] = (__bf16)oa[nt][r];
      }
  }
}

// ---------------- Temporal attention: MFMA, one wave per 16x16 block -----
__global__ __launch_bounds__(256) void attn_temporal(const __bf16* __restrict__ qkv,
                                                     __bf16* __restrict__ attn_out) {
  __shared__ __attribute__((aligned(16))) __bf16 VT[4][64 * 40];
  __shared__ __attribute__((aligned(16))) __bf16 P[4][16 * 40];
  int tid = threadIdx.x;
  {
    float4 z4 = {0.f, 0.f, 0.f, 0.f};
#pragma unroll
    for (int i = 0; i < 5; ++i) ((float4*)&VT[0][0])[tid + i * 256] = z4;
    if (tid < 64) ((float4*)&P[0][0])[tid + 256] = z4;
    ((float4*)&P[0][0])[tid] = z4;
  }
  __syncthreads();
  int bid = blockIdx.x;
  int b = bid >> 8;
  int rem = bid & 255;
  int h = 4 + (rem >> 6);
  int g = rem & 63;
  int w = tid >> 6, l = tid & 63;
  int lm = l & 15, lh = l >> 4;
  int sid = g * 4 + w;
  size_t n0 = (size_t)b * 4096 + sid * 16;

  const __bf16* qp = qkv + (n0 + lm) * 1536 + h * 64 + lh * 8;
  bf16x8 aq0 = *(const bf16x8*)qp;
  bf16x8 aq1 = *(const bf16x8*)(qp + 32);
  const __bf16* kp = qp + 512;
  bf16x8 bk0 = *(const bf16x8*)kp;
  bf16x8 bk1 = *(const bf16x8*)(kp + 32);
  int kk = l >> 2;
  int dh0 = (l & 3) * 8;
  const __bf16* vp = qkv + (n0 + kk) * 1536 + 1024 + h * 64 + dh0;
  bf16x8 vr0 = *(const bf16x8*)vp;
  bf16x8 vr1 = *(const bf16x8*)(vp + 32);

  f32x4 s4 = {0.f, 0.f, 0.f, 0.f};
  s4 = __builtin_amdgcn_mfma_f32_16x16x32_bf16(aq0, bk0, s4, 0, 0, 0);
  s4 = __builtin_amdgcn_mfma_f32_16x16x32_bf16(aq1, bk1, s4, 0, 0, 0);

#pragma unroll
  for (int d2 = 0; d2 < 8; ++d2) VT[w][(dh0 + d2) * 40 + kk] = vr0[d2];
#pragma unroll
  for (int d2 = 0; d2 < 8; ++d2) VT[w][(dh0 + 32 + d2) * 40 + kk] = vr1[d2];

  float e[4];
  float rmax[4];
#pragma unroll
  for (int r = 0; r < 4; ++r) {
    e[r] = s4[r] * 0.125f;
    rmax[r] = e[r];
  }
#pragma unroll
  for (int m = 1; m < 16; m <<= 1)
#pragma unroll
    for (int r = 0; r < 4; ++r) rmax[r] = fmaxf(rmax[r], __shfl_xor(rmax[r], m));
  float rsum[4];
#pragma unroll
  for (int r = 0; r < 4; ++r) {
    e[r] = __expf(e[r] - rmax[r]);
    rsum[r] = e[r];
  }
#pragma unroll
  for (int m = 1; m < 16; m <<= 1)
#pragma unroll
    for (int r = 0; r < 4; ++r) rsum[r] += __shfl_xor(rsum[r], m);
#pragma unroll
  for (int r = 0; r < 4; ++r)
    P[w][(lh * 4 + r) * 40 + lm] = (__bf16)(e[r] / rsum[r]);

  asm volatile("s_waitcnt lgkmcnt(0)" ::: "memory");
  __builtin_amdgcn_sched_barrier(0);

  bf16x8 pa = *(const bf16x8*)&P[w][lm * 40 + lh * 8];
#pragma unroll
  for (int nt = 0; nt < 4; ++nt) {
    bf16x8 bv = *(const bf16x8*)&VT[w][(nt * 16 + lm) * 40 + lh * 8];
    f32x4 oa = {0.f, 0.f, 0.f, 0.f};
    oa = __builtin_amdgcn_mfma_f32_16x16x32_bf16(pa, bv, oa, 0, 0, 0);
#pragma unroll
    for (int r = 0; r < 4; ++r)
      attn_out[(n0 + lh * 4 + r) * 512 + h * 64 + nt * 16 + lm] = (__bf16)oa[r];
  }
}

// ---------------- host launch ---------------------------------------------
extern "C" void kernel_launch(void* const* d_in, const int* in_sizes, int n_in,
                              void* d_out, int out_size, void* d_ws, size_t ws_size,
                              hipStream_t stream) {
  const float* x = (const float*)d_in[0];
  const float* Wqkv = (const float*)d_in[1];
  const float* Wout = (const float*)d_in[2];
  const float* bout = (const float*)d_in[3];
  const float* gamma = (const float*)d_in[4];
  const float* beta = (const float*)d_in[5];
  float* out = (float*)d_out;

  const size_t OFF_WOUT = 6291456;
  const size_t OFF_Y = OFF_WOUT + 2097152;
  const size_t OFF_QKV = OFF_Y + 33554432;
  const size_t NEEDED = OFF_QKV + 100663296;
  if (ws_size < NEEDED) return;
  char* ws = (char*)d_ws;
  __bf16* WqkvT = (__bf16*)ws;
  __bf16* WoutT = (__bf16*)(ws + OFF_WOUT);
  __bf16* ybuf = (__bf16*)(ws + OFF_Y);
  __bf16* qkv = (__bf16*)(ws + OFF_QKV);

  hipFuncSetAttribute((const void*)gemm256<1536>,
                      hipFuncAttributeMaxDynamicSharedMemorySize, 131072);
  hipFuncSetAttribute((const void*)gemm256_sb<1536>,
                      hipFuncAttributeMaxDynamicSharedMemorySize, 73728);
  hipFuncSetAttribute((const void*)gemm128res,
                      hipFuncAttributeMaxDynamicSharedMemorySize, 65536);

  transpose32<<<dim3(48, 16, 4), 256, 0, stream>>>(Wqkv, WqkvT, 512, 1536);
  transpose32<<<dim3(16, 16, 4), 256, 0, stream>>>(Wout, WoutT, 512, 512);

  for (int layer = 0; layer < 4; ++layer) {
    const float* src = (layer == 0) ? x : out;
    ln_kernel<<<8192, 256, 0, stream>>>(src, gamma + layer * 512, beta + layer * 512, ybuf);
    if (layer & 1) {
      gemm256_sb<1536><<<768, 512, 73728, stream>>>(
          ybuf, WqkvT + (size_t)layer * 1536 * 512, qkv);
    } else {
      gemm256<1536><<<768, 512, 131072, stream>>>(
          ybuf, WqkvT + (size_t)layer * 1536 * 512, qkv);
    }
    attn_spatial<<<512, 256, 0, stream>>>(qkv, ybuf);
    attn_temporal<<<2048, 256, 0, stream>>>(qkv, ybuf);
    gemm128res<<<1024, 512, 65536, stream>>>(
        ybuf, WoutT + (size_t)layer * 512 * 512, out, bout + layer * 512, src);
  }
}

// Round 12
// 647.406 us; speedup vs baseline: 1.9024x; 1.9024x over previous
//
#include <hip/hip_runtime.h>
#include <hip/hip_bf16.h>

typedef __bf16 bf16x8 __attribute__((ext_vector_type(8)));
typedef float f32x4 __attribute__((ext_vector_type(4)));

#define AS1(p) ((const __attribute__((address_space(1))) void*)(p))
#define AS3(p) ((__attribute__((address_space(3))) void*)(p))

// ---------------- tiled cast+transpose fp32(L,K,N) -> bf16(L,N,K) --------
__global__ __launch_bounds__(256) void transpose32(const float* __restrict__ W,
                                                   __bf16* __restrict__ WT,
                                                   int K, int N) {
  __shared__ float t[32][33];
  int l = blockIdx.z;
  int k0 = blockIdx.y * 32, n0 = blockIdx.x * 32;
  int tx = threadIdx.x & 31, ty = threadIdx.x >> 5;
  const float* src = W + ((size_t)l * K + k0) * N + n0;
#pragma unroll
  for (int i = 0; i < 32; i += 8) t[ty + i][tx] = src[(size_t)(ty + i) * N + tx];
  __syncthreads();
  __bf16* dst = WT + ((size_t)l * N + n0) * K + k0;
#pragma unroll
  for (int i = 0; i < 32; i += 8) dst[(size_t)(ty + i) * K + tx] = (__bf16)t[tx][ty + i];
}

// ---------------- LayerNorm: fp32 row(512) -> bf16 ----------------------
__global__ __launch_bounds__(256) void ln_kernel(const float* __restrict__ x,
                                                 const float* __restrict__ gamma,
                                                 const float* __restrict__ beta,
                                                 __bf16* __restrict__ y) {
  int wave = threadIdx.x >> 6, lane = threadIdx.x & 63;
  size_t row = (size_t)blockIdx.x * 4 + wave;
  const float* xr = x + row * 512 + lane * 8;
  float4 v0 = *(const float4*)xr;
  float4 v1 = *(const float4*)(xr + 4);
  float s = v0.x + v0.y + v0.z + v0.w + v1.x + v1.y + v1.z + v1.w;
  float ss = v0.x * v0.x + v0.y * v0.y + v0.z * v0.z + v0.w * v0.w +
             v1.x * v1.x + v1.y * v1.y + v1.z * v1.z + v1.w * v1.w;
#pragma unroll
  for (int m = 1; m < 64; m <<= 1) {
    s += __shfl_xor(s, m);
    ss += __shfl_xor(ss, m);
  }
  float mean = s * (1.f / 512.f);
  float var = ss * (1.f / 512.f) - mean * mean;
  float rstd = rsqrtf(var + 1e-5f);
  const float* gp = gamma + lane * 8;
  const float* bp = beta + lane * 8;
  float4 g0 = *(const float4*)gp, g1 = *(const float4*)(gp + 4);
  float4 b0 = *(const float4*)bp, b1 = *(const float4*)(bp + 4);
  bf16x8 o;
  o[0] = (__bf16)((v0.x - mean) * rstd * g0.x + b0.x);
  o[1] = (__bf16)((v0.y - mean) * rstd * g0.y + b0.y);
  o[2] = (__bf16)((v0.z - mean) * rstd * g0.z + b0.z);
  o[3] = (__bf16)((v0.w - mean) * rstd * g0.w + b0.w);
  o[4] = (__bf16)((v1.x - mean) * rstd * g1.x + b1.x);
  o[5] = (__bf16)((v1.y - mean) * rstd * g1.y + b1.y);
  o[6] = (__bf16)((v1.z - mean) * rstd * g1.z + b1.z);
  o[7] = (__bf16)((v1.w - mean) * rstd * g1.w + b1.w);
  *(bf16x8*)(y + row * 512 + lane * 8) = o;
}

// ---------------- 256x256 deep-pipelined GEMM (QKV) — R9/R7 schedule ------
#define STAGE_PART(kt_, part_)                                                   \
  {                                                                              \
    const __bf16* gb_ = ((part_) < 2) ? Abase : Bbase;                           \
    int rowoff_ = ((part_)&1) * 128;                                             \
    const __bf16* g0_ = gb_ + (size_t)(rowoff_ + r0s) * 512 + (kt_)*64 + s0 * 8; \
    const __bf16* g1_ = gb_ + (size_t)(rowoff_ + r1s) * 512 + (kt_)*64 + s1 * 8; \
    char* lb_ = lds + (((kt_)&1) * 65536) + ((part_)*16384);                     \
    __builtin_amdgcn_global_load_lds(AS1(g0_), AS3(lb_ + ldsw0), 16, 0, 0);      \
    __builtin_amdgcn_global_load_lds(AS1(g1_), AS3(lb_ + ldsw1), 16, 0, 0);      \
  }

template <int NCOLS>
__global__ __launch_bounds__(512, 2) void gemm256(const __bf16* __restrict__ A,
                                                  const __bf16* __restrict__ BT,
                                                  __bf16* __restrict__ Cb) {
  extern __shared__ __attribute__((aligned(128))) char lds[];
  constexpr int NT = NCOLS / 256;
  int bid = blockIdx.x;
  int cpx = gridDim.x >> 3;
  int L = (bid & 7) * cpx + (bid >> 3);
  int tileM = L / NT, tileN = L - tileM * NT;
  int tid = threadIdx.x;
  int l = tid & 63, w = tid >> 6;
  int lm = l & 15, lh = l >> 4;
  int wave_m = w >> 2, wave_n = w & 3;
  const __bf16* Abase = A + (size_t)tileM * 256 * 512;
  const __bf16* Bbase = BT + (size_t)tileN * 256 * 512;
  int r0s = tid >> 3, s0 = (tid & 7) ^ (r0s & 7);
  int p1 = tid + 512;
  int r1s = p1 >> 3, s1 = (p1 & 7) ^ (r1s & 7);
  int ldsw0 = (w * 64) * 16, ldsw1 = (512 + w * 64) * 16;

  f32x4 acc[8][4];
#pragma unroll
  for (int m = 0; m < 8; ++m)
#pragma unroll
    for (int n = 0; n < 4; ++n) acc[m][n] = (f32x4){0.f, 0.f, 0.f, 0.f};

  int xorv = (lm & 7) << 4;
  int kb0 = (lh * 16) ^ xorv;
  int kb1 = (64 + lh * 16) ^ xorv;
  int arow = wave_m * 128 + lm;
  int brow = wave_n * 64 + lm;

  STAGE_PART(0, 0); STAGE_PART(0, 1); STAGE_PART(0, 2); STAGE_PART(0, 3);

  for (int kt = 0; kt < 8; ++kt) {
    char* sb = lds + (kt & 1) * 65536;
    if (kt < 7) {
      STAGE_PART(kt + 1, 0);
      asm volatile("s_waitcnt vmcnt(2)" ::: "memory");
    } else {
      asm volatile("s_waitcnt vmcnt(0)" ::: "memory");
    }
    __builtin_amdgcn_sched_barrier(0);
    __builtin_amdgcn_s_barrier();
    bf16x8 bfrag[4][2];
#pragma unroll
    for (int nf = 0; nf < 4; ++nf) {
      const char* bp = sb + 32768 + (brow + nf * 16) * 128;
      bfrag[nf][0] = *(const bf16x8*)(bp + kb0);
      bfrag[nf][1] = *(const bf16x8*)(bp + kb1);
    }
#pragma unroll
    for (int ph = 0; ph < 4; ++ph) {
      bf16x8 af[2][2];
#pragma unroll
      for (int m = 0; m < 2; ++m) {
        const char* ap = sb + (arow + (ph * 2 + m) * 16) * 128;
        af[m][0] = *(const bf16x8*)(ap + kb0);
        af[m][1] = *(const bf16x8*)(ap + kb1);
      }
      if (ph == 0 && kt < 7) STAGE_PART(kt + 1, 1);
      if (ph == 1 && kt < 7) STAGE_PART(kt + 1, 2);
      if (ph == 2 && kt < 7) STAGE_PART(kt + 1, 3);
      __builtin_amdgcn_s_setprio(1);
#pragma unroll
      for (int m = 0; m < 2; ++m)
#pragma unroll
        for (int nf = 0; nf < 4; ++nf) {
          acc[ph * 2 + m][nf] = __builtin_amdgcn_mfma_f32_16x16x32_bf16(
              af[m][0], bfrag[nf][0], acc[ph * 2 + m][nf], 0, 0, 0);
          acc[ph * 2 + m][nf] = __builtin_amdgcn_mfma_f32_16x16x32_bf16(
              af[m][1], bfrag[nf][1], acc[ph * 2 + m][nf], 0, 0, 0);
        }
      __builtin_amdgcn_s_setprio(0);
    }
    __builtin_amdgcn_s_barrier();
  }

  // ---- coalesced epilogue: two-pass, stride-72 ----
  __syncthreads();
  __bf16* lw = (__bf16*)(lds + w * 9216);
  int crow0 = tileM * 256 + wave_m * 128;
  int ccol = tileN * 256 + wave_n * 64 + (l & 7) * 8;
#pragma unroll
  for (int half = 0; half < 2; ++half) {
#pragma unroll
    for (int m2 = 0; m2 < 4; ++m2) {
      int mf = half * 4 + m2;
#pragma unroll
      for (int nf = 0; nf < 4; ++nf)
#pragma unroll
        for (int r = 0; r < 4; ++r)
          lw[(m2 * 16 + lh * 4 + r) * 72 + nf * 16 + lm] = (__bf16)acc[mf][nf][r];
    }
    asm volatile("s_waitcnt lgkmcnt(0)" ::: "memory");
    __builtin_amdgcn_sched_barrier(0);
#pragma unroll
    for (int p = 0; p < 8; ++p) {
      int lrow = p * 8 + (l >> 3);
      bf16x8 v = *(const bf16x8*)&lw[lrow * 72 + (l & 7) * 8];
      *(bf16x8*)&Cb[(size_t)(crow0 + half * 64 + lrow) * NCOLS + ccol] = v;
    }
    asm volatile("s_waitcnt lgkmcnt(0)" ::: "memory");
    __builtin_amdgcn_sched_barrier(0);
  }
}

// ---------- Variant B (fixed): 128x256, BK=64, single-buffer, acc[4][4] ----
// 48 KiB LDS, no launch-bounds VGPR cap (acc 64 + frags ~48 + addr -> ~120
// VGPR predicted -> 16 waves/CU = 2 blocks resident). Stage stall exposed
// per block, covered by co-resident block's MFMA phase (cross-block TLP).
#define STAGE_SB(kt_)                                                            \
  {                                                                              \
    const __bf16* gA0_ = Abase + (size_t)rA0 * 512 + (kt_)*64 + sA0 * 8;         \
    const __bf16* gA1_ = Abase + (size_t)rA1 * 512 + (kt_)*64 + sA1 * 8;         \
    __builtin_amdgcn_global_load_lds(AS1(gA0_), AS3(lds + dW0), 16, 0, 0);       \
    __builtin_amdgcn_global_load_lds(AS1(gA1_), AS3(lds + 8192 + dW0), 16, 0, 0);\
    __builtin_amdgcn_global_load_lds(AS1(Bbase + (size_t)rA0 * 512 + (kt_)*64 + sA0 * 8), \
                                     AS3(lds + 16384 + dW0), 16, 0, 0);          \
    __builtin_amdgcn_global_load_lds(AS1(Bbase + (size_t)rA1 * 512 + (kt_)*64 + sA1 * 8), \
                                     AS3(lds + 24576 + dW0), 16, 0, 0);          \
    __builtin_amdgcn_global_load_lds(AS1(Bbase + (size_t)(128 + rA0) * 512 + (kt_)*64 + sA0 * 8), \
                                     AS3(lds + 32768 + dW0), 16, 0, 0);          \
    __builtin_amdgcn_global_load_lds(AS1(Bbase + (size_t)(128 + rA1) * 512 + (kt_)*64 + sA1 * 8), \
                                     AS3(lds + 40960 + dW0), 16, 0, 0);          \
  }

__global__ __launch_bounds__(512) void gemm_sb(const __bf16* __restrict__ A,
                                               const __bf16* __restrict__ BT,
                                               __bf16* __restrict__ Cb) {
  extern __shared__ __attribute__((aligned(128))) char lds[];
  constexpr int NCOLS = 1536;
  constexpr int NT = 6;  // N-tiles of 256
  int bid = blockIdx.x;
  int cpx = gridDim.x >> 3;
  int L = (bid & 7) * cpx + (bid >> 3);
  int tileM = L / NT, tileN = L - tileM * NT;
  int tid = threadIdx.x;
  int l = tid & 63, w = tid >> 6;
  int lm = l & 15, lh = l >> 4;
  int wave_m = w >> 2, wave_n = w & 3;  // 2M x 4N, wave tile 64x64
  const __bf16* Abase = A + (size_t)tileM * 128 * 512;
  const __bf16* Bbase = BT + (size_t)tileN * 256 * 512;
  // staging: chunk p -> row p>>3, phys c=p&7, logical s = c ^ (row&7)
  int rA0 = tid >> 3, sA0 = (tid & 7) ^ (rA0 & 7);
  int p1 = tid + 512;
  int rA1 = p1 >> 3, sA1 = (p1 & 7) ^ (rA1 & 7);
  int dW0 = w * 1024;  // wave-uniform dest

  f32x4 acc[4][4];
#pragma unroll
  for (int m = 0; m < 4; ++m)
#pragma unroll
    for (int n = 0; n < 4; ++n) acc[m][n] = (f32x4){0.f, 0.f, 0.f, 0.f};

  int xorv = (lm & 7) << 4;
  int kb0 = (lh * 16) ^ xorv;
  int kb1 = (64 + lh * 16) ^ xorv;
  int arow = wave_m * 64 + lm;
  int brow = wave_n * 64 + lm;

  // prologue
  STAGE_SB(0);
  asm volatile("s_waitcnt vmcnt(0)" ::: "memory");
  __builtin_amdgcn_sched_barrier(0);
  __builtin_amdgcn_s_barrier();

  for (int kt = 0; kt < 8; ++kt) {
    bf16x8 bfrag[4][2];
#pragma unroll
    for (int nf = 0; nf < 4; ++nf) {
      const char* bp = lds + 16384 + (brow + nf * 16) * 128;
      bfrag[nf][0] = *(const bf16x8*)(bp + kb0);
      bfrag[nf][1] = *(const bf16x8*)(bp + kb1);
    }
    __builtin_amdgcn_s_setprio(1);
#pragma unroll
    for (int mf = 0; mf < 4; ++mf) {
      const char* ap = lds + (arow + mf * 16) * 128;
      bf16x8 af0 = *(const bf16x8*)(ap + kb0);
      bf16x8 af1 = *(const bf16x8*)(ap + kb1);
#pragma unroll
      for (int nf = 0; nf < 4; ++nf) {
        acc[mf][nf] = __builtin_amdgcn_mfma_f32_16x16x32_bf16(af0, bfrag[nf][0],
                                                              acc[mf][nf], 0, 0, 0);
        acc[mf][nf] = __builtin_amdgcn_mfma_f32_16x16x32_bf16(af1, bfrag[nf][1],
                                                              acc[mf][nf], 0, 0, 0);
      }
    }
    __builtin_amdgcn_s_setprio(0);
    // all waves done READING the buffer before anyone overwrites it
    asm volatile("s_waitcnt lgkmcnt(0)" ::: "memory");
    __builtin_amdgcn_sched_barrier(0);
    __builtin_amdgcn_s_barrier();
    if (kt < 7) {
      STAGE_SB(kt + 1);
      asm volatile("s_waitcnt vmcnt(0)" ::: "memory");
      __builtin_amdgcn_sched_barrier(0);
      __builtin_amdgcn_s_barrier();
    }
  }

  // ---- epilogue: two-pass (32 rows each), stride-72 bounce ----
  __syncthreads();
  __bf16* lw = (__bf16*)(lds + w * 4608);  // wave-private [32][72]
  int crow0 = tileM * 128 + wave_m * 64;
  int ccol = tileN * 256 + wave_n * 64 + (l & 7) * 8;
#pragma unroll
  for (int half = 0; half < 2; ++half) {
#pragma unroll
    for (int m2 = 0; m2 < 2; ++m2) {
      int mf = half * 2 + m2;
#pragma unroll
      for (int nf = 0; nf < 4; ++nf)
#pragma unroll
        for (int r = 0; r < 4; ++r)
          lw[(m2 * 16 + lh * 4 + r) * 72 + nf * 16 + lm] = (__bf16)acc[mf][nf][r];
    }
    asm volatile("s_waitcnt lgkmcnt(0)" ::: "memory");
    __builtin_amdgcn_sched_barrier(0);
#pragma unroll
    for (int p = 0; p < 4; ++p) {
      int lrow = p * 8 + (l >> 3);
      bf16x8 v = *(const bf16x8*)&lw[lrow * 72 + (l & 7) * 8];
      *(bf16x8*)&Cb[(size_t)(crow0 + half * 32 + lrow) * NCOLS + ccol] = v;
    }
    asm volatile("s_waitcnt lgkmcnt(0)" ::: "memory");
    __builtin_amdgcn_sched_barrier(0);
  }
}

// ---------------- 128x128 GEMM + fused bias/residual, 8 waves (R9) -------
#define STAGE128(kt_, part_)                                                    \
  {                                                                             \
    const __bf16* gb_ = ((part_) == 0) ? Abase : Bbase;                         \
    const __bf16* g0_ = gb_ + (size_t)r0s * 512 + (kt_)*64 + s0 * 8;            \
    const __bf16* g1_ = gb_ + (size_t)r1s * 512 + (kt_)*64 + s1 * 8;            \
    char* lb_ = lds + (((kt_)&1) * 32768) + ((part_)*16384);                    \
    __builtin_amdgcn_global_load_lds(AS1(g0_), AS3(lb_ + ldsw0), 16, 0, 0);     \
    __builtin_amdgcn_global_load_lds(AS1(g1_), AS3(lb_ + ldsw1), 16, 0, 0);     \
  }

__global__ __launch_bounds__(512, 4) void gemm128res(const __bf16* __restrict__ A,
                                                     const __bf16* __restrict__ BT,
                                                     float* Cf,
                                                     const float* __restrict__ bias,
                                                     const float* Resid) {
  extern __shared__ __attribute__((aligned(128))) char lds[];
  constexpr int NCOLS = 512;
  constexpr int NT = 4;
  int bid = blockIdx.x;
  int cpx = gridDim.x >> 3;
  int L = (bid & 7) * cpx + (bid >> 3);
  int tileM = L / NT, tileN = L - tileM * NT;
  int tid = threadIdx.x;
  int l = tid & 63, w = tid >> 6;
  int lm = l & 15, lh = l >> 4;
  int wave_m = w >> 2, wave_n = w & 3;
  const __bf16* Abase = A + (size_t)tileM * 128 * 512;
  const __bf16* Bbase = BT + (size_t)tileN * 128 * 512;
  int r0s = tid >> 3, s0 = (tid & 7) ^ (r0s & 7);
  int p1 = tid + 512;
  int r1s = p1 >> 3, s1 = (p1 & 7) ^ (r1s & 7);
  int ldsw0 = (w * 64) * 16, ldsw1 = 8192 + (w * 64) * 16;

  f32x4 acc[4][2];
#pragma unroll
  for (int m = 0; m < 4; ++m)
#pragma unroll
    for (int n = 0; n < 2; ++n) acc[m][n] = (f32x4){0.f, 0.f, 0.f, 0.f};

  int xorv = (lm & 7) << 4;
  int kb0 = (lh * 16) ^ xorv;
  int kb1 = (64 + lh * 16) ^ xorv;
  int arow = wave_m * 64 + lm;
  int brow = wave_n * 32 + lm;

  STAGE128(0, 0); STAGE128(0, 1);

  for (int kt = 0; kt < 8; ++kt) {
    char* sb = lds + (kt & 1) * 32768;
    if (kt < 7) {
      STAGE128(kt + 1, 0);
      asm volatile("s_waitcnt vmcnt(2)" ::: "memory");
    } else {
      asm volatile("s_waitcnt vmcnt(0)" ::: "memory");
    }
    __builtin_amdgcn_sched_barrier(0);
    __builtin_amdgcn_s_barrier();
    bf16x8 bfrag[2][2];
#pragma unroll
    for (int nf = 0; nf < 2; ++nf) {
      const char* bp = sb + 16384 + (brow + nf * 16) * 128;
      bfrag[nf][0] = *(const bf16x8*)(bp + kb0);
      bfrag[nf][1] = *(const bf16x8*)(bp + kb1);
    }
    bf16x8 af[4][2];
#pragma unroll
    for (int mf = 0; mf < 4; ++mf) {
      const char* ap = sb + (arow + mf * 16) * 128;
      af[mf][0] = *(const bf16x8*)(ap + kb0);
      af[mf][1] = *(const bf16x8*)(ap + kb1);
    }
    if (kt < 7) STAGE128(kt + 1, 1);
    __builtin_amdgcn_s_setprio(1);
#pragma unroll
    for (int mf = 0; mf < 4; ++mf)
#pragma unroll
      for (int nf = 0; nf < 2; ++nf) {
        acc[mf][nf] = __builtin_amdgcn_mfma_f32_16x16x32_bf16(af[mf][0], bfrag[nf][0],
                                                              acc[mf][nf], 0, 0, 0);
        acc[mf][nf] = __builtin_amdgcn_mfma_f32_16x16x32_bf16(af[mf][1], bfrag[nf][1],
                                                              acc[mf][nf], 0, 0, 0);
      }
    __builtin_amdgcn_s_setprio(0);
    __builtin_amdgcn_s_barrier();
  }

  float* lf = (float*)(lds + w * 2560);
  int crow0 = tileM * 128 + wave_m * 64;
  int ccol0 = tileN * 128 + wave_n * 32;
  int erow = l >> 2;
  int ecl = (l & 3) * 8;
  float4 ba = *(const float4*)(bias + ccol0 + ecl);
  float4 bb = *(const float4*)(bias + ccol0 + ecl + 4);
#pragma unroll
  for (int mf = 0; mf < 4; ++mf) {
#pragma unroll
    for (int nf = 0; nf < 2; ++nf)
#pragma unroll
      for (int r = 0; r < 4; ++r)
        lf[(lh * 4 + r) * 40 + nf * 16 + lm] = acc[mf][nf][r];
    size_t rowg = (size_t)(crow0 + mf * 16 + erow);
    const float* rp = Resid + rowg * NCOLS + ccol0 + ecl;
    float* cp = Cf + rowg * NCOLS + ccol0 + ecl;
    float4 a0 = *(float4*)&lf[erow * 40 + ecl];
    float4 a1 = *(float4*)&lf[erow * 40 + ecl + 4];
    float4 r0 = *(const float4*)rp;
    float4 r1 = *(const float4*)(rp + 4);
    float4 o0, o1;
    o0.x = a0.x + ba.x + r0.x; o0.y = a0.y + ba.y + r0.y;
    o0.z = a0.z + ba.z + r0.z; o0.w = a0.w + ba.w + r0.w;
    o1.x = a1.x + bb.x + r1.x; o1.y = a1.y + bb.y + r1.y;
    o1.z = a1.z + bb.z + r1.z; o1.w = a1.w + bb.w + r1.w;
    *(float4*)cp = o0;
    *(float4*)(cp + 4) = o1;
  }
}

// ---------------- Spatial attention: per (b, h<4, t) block ----------------
__global__ __launch_bounds__(256) void attn_spatial(const __bf16* __restrict__ qkv,
                                                    __bf16* __restrict__ attn_out) {
  __shared__ __attribute__((aligned(16))) __bf16 VT[64 * 256];
  __shared__ __attribute__((aligned(16))) __bf16 P[4][4096];
  int bid = blockIdx.x;
  int b = bid >> 6;
  int rem = bid & 63;
  int h = rem >> 4;
  int t = rem & 15;
  int tid = threadIdx.x;
  int w = tid >> 6, l = tid & 63;
  size_t nbase = (size_t)b * 4096 + t * 256;
#pragma unroll
  for (int i = 0; i < 8; i++) {
    int idx = tid + i * 256;
    int key = idx >> 3, dseg = idx & 7;
    bf16x8 v = *(const bf16x8*)(qkv + (nbase + key) * 1536 + 1024 + h * 64 + dseg * 8);
#pragma unroll
    for (int d2 = 0; d2 < 8; d2++) {
      int dh = dseg * 8 + d2;
      VT[dh * 256 + (((key >> 3) ^ (dh & 7)) << 3) + (key & 7)] = v[d2];
    }
  }
  __syncthreads();
  int lm = l & 15, lh = l >> 4;
  for (int it = 0; it < 4; ++it) {
    int qbase = it * 64 + w * 16;
    const __bf16* qp = qkv + (nbase + qbase + lm) * 1536 + h * 64 + lh * 8;
    bf16x8 aq0 = *(const bf16x8*)qp;
    bf16x8 aq1 = *(const bf16x8*)(qp + 32);
    f32x4 sa[16];
#pragma unroll
    for (int tn = 0; tn < 16; ++tn) {
      const __bf16* kp = qkv + (nbase + tn * 16 + lm) * 1536 + 512 + h * 64 + lh * 8;
      bf16x8 bk0 = *(const bf16x8*)kp;
      bf16x8 bk1 = *(const bf16x8*)(kp + 32);
      f32x4 z = {0.f, 0.f, 0.f, 0.f};
      z = __builtin_amdgcn_mfma_f32_16x16x32_bf16(aq0, bk0, z, 0, 0, 0);
      sa[tn] = __builtin_amdgcn_mfma_f32_16x16x32_bf16(aq1, bk1, z, 0, 0, 0);
    }
    float rmax[4] = {-1e30f, -1e30f, -1e30f, -1e30f};
#pragma unroll
    for (int tn = 0; tn < 16; ++tn)
#pragma unroll
      for (int r = 0; r < 4; ++r) {
        sa[tn][r] *= 0.125f;
        rmax[r] = fmaxf(rmax[r], sa[tn][r]);
      }
#pragma unroll
    for (int m = 1; m < 16; m <<= 1)
#pragma unroll
      for (int r = 0; r < 4; ++r) rmax[r] = fmaxf(rmax[r], __shfl_xor(rmax[r], m));
    float rsum[4] = {0.f, 0.f, 0.f, 0.f};
#pragma unroll
    for (int tn = 0; tn < 16; ++tn)
#pragma unroll
      for (int r = 0; r < 4; ++r) {
        float e = __expf(sa[tn][r] - rmax[r]);
        sa[tn][r] = e;
        rsum[r] += e;
      }
#pragma unroll
    for (int m = 1; m < 16; m <<= 1)
#pragma unroll
      for (int r = 0; r < 4; ++r) rsum[r] += __shfl_xor(rsum[r], m);
    float rinv[4];
#pragma unroll
    for (int r = 0; r < 4; ++r) rinv[r] = 1.f / rsum[r];
#pragma unroll
    for (int tn = 0; tn < 16; ++tn)
#pragma unroll
      for (int r = 0; r < 4; ++r) {
        int row = lh * 4 + r;
        int col = tn * 16 + lm;
        P[w][row * 256 + ((((col >> 3)) ^ (row & 7)) << 3) + (col & 7)] =
            (__bf16)(sa[tn][r] * rinv[r]);
      }
    f32x4 oa[4];
#pragma unroll
    for (int nt = 0; nt < 4; ++nt) oa[nt] = (f32x4){0.f, 0.f, 0.f, 0.f};
#pragma unroll
    for (int kc = 0; kc < 8; ++kc) {
      bf16x8 pa = *(const bf16x8*)&P[w][lm * 256 + (((kc * 4 + lh) ^ (lm & 7)) << 3)];
#pragma unroll
      for (int nt = 0; nt < 4; ++nt) {
        int dh = nt * 16 + lm;
        bf16x8 bv = *(const bf16x8*)&VT[dh * 256 + (((kc * 4 + lh) ^ (dh & 7)) << 3)];
        oa[nt] = __builtin_amdgcn_mfma_f32_16x16x32_bf16(pa, bv, oa[nt], 0, 0, 0);
      }
    }
#pragma unroll
    for (int nt = 0; nt < 4; ++nt)
#pragma unroll
      for (int r = 0; r < 4; ++r) {
        size_t row = nbase + qbase + lh * 4 + r;
        attn_out[row * 512 + h * 64 + nt * 16 + lm] = (__bf16)oa[nt][r];
      }
  }
}

// ---------------- Temporal attention: MFMA, one wave per 16x16 block -----
__global__ __launch_bounds__(256) void attn_temporal(const __bf16* __restrict__ qkv,
                                                     __bf16* __restrict__ attn_out) {
  __shared__ __attribute__((aligned(16))) __bf16 VT[4][64 * 40];
  __shared__ __attribute__((aligned(16))) __bf16 P[4][16 * 40];
  int tid = threadIdx.x;
  {
    float4 z4 = {0.f, 0.f, 0.f, 0.f};
#pragma unroll
    for (int i = 0; i < 5; ++i) ((float4*)&VT[0][0])[tid + i * 256] = z4;
    if (tid < 64) ((float4*)&P[0][0])[tid + 256] = z4;
    ((float4*)&P[0][0])[tid] = z4;
  }
  __syncthreads();
  int bid = blockIdx.x;
  int b = bid >> 8;
  int rem = bid & 255;
  int h = 4 + (rem >> 6);
  int g = rem & 63;
  int w = tid >> 6, l = tid & 63;
  int lm = l & 15, lh = l >> 4;
  int sid = g * 4 + w;
  size_t n0 = (size_t)b * 4096 + sid * 16;

  const __bf16* qp = qkv + (n0 + lm) * 1536 + h * 64 + lh * 8;
  bf16x8 aq0 = *(const bf16x8*)qp;
  bf16x8 aq1 = *(const bf16x8*)(qp + 32);
  const __bf16* kp = qp + 512;
  bf16x8 bk0 = *(const bf16x8*)kp;
  bf16x8 bk1 = *(const bf16x8*)(kp + 32);
  int kk = l >> 2;
  int dh0 = (l & 3) * 8;
  const __bf16* vp = qkv + (n0 + kk) * 1536 + 1024 + h * 64 + dh0;
  bf16x8 vr0 = *(const bf16x8*)vp;
  bf16x8 vr1 = *(const bf16x8*)(vp + 32);

  f32x4 s4 = {0.f, 0.f, 0.f, 0.f};
  s4 = __builtin_amdgcn_mfma_f32_16x16x32_bf16(aq0, bk0, s4, 0, 0, 0);
  s4 = __builtin_amdgcn_mfma_f32_16x16x32_bf16(aq1, bk1, s4, 0, 0, 0);

#pragma unroll
  for (int d2 = 0; d2 < 8; ++d2) VT[w][(dh0 + d2) * 40 + kk] = vr0[d2];
#pragma unroll
  for (int d2 = 0; d2 < 8; ++d2) VT[w][(dh0 + 32 + d2) * 40 + kk] = vr1[d2];

  float e[4];
  float rmax[4];
#pragma unroll
  for (int r = 0; r < 4; ++r) {
    e[r] = s4[r] * 0.125f;
    rmax[r] = e[r];
  }
#pragma unroll
  for (int m = 1; m < 16; m <<= 1)
#pragma unroll
    for (int r = 0; r < 4; ++r) rmax[r] = fmaxf(rmax[r], __shfl_xor(rmax[r], m));
  float rsum[4];
#pragma unroll
  for (int r = 0; r < 4; ++r) {
    e[r] = __expf(e[r] - rmax[r]);
    rsum[r] = e[r];
  }
#pragma unroll
  for (int m = 1; m < 16; m <<= 1)
#pragma unroll
    for (int r = 0; r < 4; ++r) rsum[r] += __shfl_xor(rsum[r], m);
#pragma unroll
  for (int r = 0; r < 4; ++r)
    P[w][(lh * 4 + r) * 40 + lm] = (__bf16)(e[r] / rsum[r]);

  asm volatile("s_waitcnt lgkmcnt(0)" ::: "memory");
  __builtin_amdgcn_sched_barrier(0);

  bf16x8 pa = *(const bf16x8*)&P[w][lm * 40 + lh * 8];
#pragma unroll
  for (int nt = 0; nt < 4; ++nt) {
    bf16x8 bv = *(const bf16x8*)&VT[w][(nt * 16 + lm) * 40 + lh * 8];
    f32x4 oa = {0.f, 0.f, 0.f, 0.f};
    oa = __builtin_amdgcn_mfma_f32_16x16x32_bf16(pa, bv, oa, 0, 0, 0);
#pragma unroll
    for (int r = 0; r < 4; ++r)
      attn_out[(n0 + lh * 4 + r) * 512 + h * 64 + nt * 16 + lm] = (__bf16)oa[r];
  }
}

// ---------------- host launch ---------------------------------------------
extern "C" void kernel_launch(void* const* d_in, const int* in_sizes, int n_in,
                              void* d_out, int out_size, void* d_ws, size_t ws_size,
                              hipStream_t stream) {
  const float* x = (const float*)d_in[0];
  const float* Wqkv = (const float*)d_in[1];
  const float* Wout = (const float*)d_in[2];
  const float* bout = (const float*)d_in[3];
  const float* gamma = (const float*)d_in[4];
  const float* beta = (const float*)d_in[5];
  float* out = (float*)d_out;

  const size_t OFF_WOUT = 6291456;
  const size_t OFF_Y = OFF_WOUT + 2097152;
  const size_t OFF_QKV = OFF_Y + 33554432;
  const size_t NEEDED = OFF_QKV + 100663296;
  if (ws_size < NEEDED) return;
  char* ws = (char*)d_ws;
  __bf16* WqkvT = (__bf16*)ws;
  __bf16* WoutT = (__bf16*)(ws + OFF_WOUT);
  __bf16* ybuf = (__bf16*)(ws + OFF_Y);
  __bf16* qkv = (__bf16*)(ws + OFF_QKV);

  hipFuncSetAttribute((const void*)gemm256<1536>,
                      hipFuncAttributeMaxDynamicSharedMemorySize, 131072);
  hipFuncSetAttribute((const void*)gemm_sb,
                      hipFuncAttributeMaxDynamicSharedMemorySize, 49152);
  hipFuncSetAttribute((const void*)gemm128res,
                      hipFuncAttributeMaxDynamicSharedMemorySize, 65536);

  transpose32<<<dim3(48, 16, 4), 256, 0, stream>>>(Wqkv, WqkvT, 512, 1536);
  transpose32<<<dim3(16, 16, 4), 256, 0, stream>>>(Wout, WoutT, 512, 512);

  for (int layer = 0; layer < 4; ++layer) {
    const float* src = (layer == 0) ? x : out;
    ln_kernel<<<8192, 256, 0, stream>>>(src, gamma + layer * 512, beta + layer * 512, ybuf);
    if (layer & 1) {
      gemm_sb<<<1536, 512, 49152, stream>>>(
          ybuf, WqkvT + (size_t)layer * 1536 * 512, qkv);
    } else {
      gemm256<1536><<<768, 512, 131072, stream>>>(
          ybuf, WqkvT + (size_t)layer * 1536 * 512, qkv);
    }
    attn_spatial<<<512, 256, 0, stream>>>(qkv, ybuf);
    attn_temporal<<<2048, 256, 0, stream>>>(qkv, ybuf);
    gemm128res<<<1024, 512, 65536, stream>>>(
        ybuf, WoutT + (size_t)layer * 512 * 512, out, bout + layer * 512, src);
  }
}